// Round 12
// baseline (191.503 us; speedup 1.0000x reference)
//
#include <hip/hip_runtime.h>
#include <math.h>

#define N_PTS 65536
#define M_IND 1024
#define KNN 16
#define JITTER 1e-4f

// Packed lower-triangular Su: P[i*(i+1)/2 + j], j <= i.
#define PACKED_FLOATS (M_IND * (M_IND + 1) / 2)               // 524800
#define PACKED_BYTES  ((size_t)PACKED_FLOATS * sizeof(float)) // 2,099,200 B

#define TSU 32
#define SU_BLOCKS 528          // 32*33/2 triangular tiles
#define PTS_PER_BLK 128
#define QSTRIDE 25             // u64 per point row (200 B): 8x12 u16 collect / 16 u64 hand
#define GRID_BLKS (N_PTS / PTS_PER_BLK)   // 512

typedef float v2f __attribute__((ext_vector_type(2)));

// ---------------------------------------------------------------------------
// One 32x32 Su tile (packed tril(Lu Lu^T)). As/Bs are LDS scratch.
// ---------------------------------------------------------------------------
__device__ __forceinline__ void su_tile(const float* __restrict__ Lu_raw,
                                        float* __restrict__ P,
                                        int bid, int tid,
                                        float (*As)[36], float (*Bs)[36]) {
    int rt = (int)((sqrtf(8.0f * (float)bid + 1.0f) - 1.0f) * 0.5f);
    while ((rt + 1) * (rt + 2) / 2 <= bid) ++rt;
    while (rt * (rt + 1) / 2 > bid) --rt;
    int ct = bid - rt * (rt + 1) / 2;   // ct <= rt
    int i0 = rt * TSU, j0 = ct * TSU;

    int tx = tid & 15, ty = tid >> 4;
    int sr = tid >> 3, sc = (tid & 7) << 2;
    float a00 = 0.f, a01 = 0.f, a10 = 0.f, a11 = 0.f;

    int nch = ct + 1;                      // k-chunks of 32 (k <= j0+31)
    int gi = i0 + sr, gj = j0 + sr;
    float4 pa = *(const float4*)(Lu_raw + (unsigned)gi * M_IND + sc);
    float4 pb = *(const float4*)(Lu_raw + (unsigned)gj * M_IND + sc);

    for (int c = 0; c < nch; ++c) {
        int gk = (c << 5) + sc;
        float aa[4] = {pa.x, pa.y, pa.z, pa.w};
        float bb[4] = {pb.x, pb.y, pb.z, pb.w};
        #pragma unroll
        for (int q = 0; q < 4; ++q) {
            int k = gk + q;
            aa[q] = (k < gi) ? aa[q] : ((k == gi) ? __expf(aa[q]) : 0.0f);
            bb[q] = (k < gj) ? bb[q] : ((k == gj) ? __expf(bb[q]) : 0.0f);
        }
        *(float4*)&As[sr][sc] = make_float4(aa[0], aa[1], aa[2], aa[3]);
        *(float4*)&Bs[sr][sc] = make_float4(bb[0], bb[1], bb[2], bb[3]);
        __syncthreads();
        if (c + 1 < nch) {
            int kn = ((c + 1) << 5) + sc;
            pa = *(const float4*)(Lu_raw + (unsigned)gi * M_IND + kn);
            pb = *(const float4*)(Lu_raw + (unsigned)gj * M_IND + kn);
        }
        #pragma unroll
        for (int kk = 0; kk < 32; kk += 4) {
            float4 av0 = *(const float4*)&As[ty][kk];
            float4 av1 = *(const float4*)&As[ty + 16][kk];
            float4 bv0 = *(const float4*)&Bs[tx][kk];
            float4 bv1 = *(const float4*)&Bs[tx + 16][kk];
            a00 = fmaf(av0.x, bv0.x, fmaf(av0.y, bv0.y, fmaf(av0.z, bv0.z, fmaf(av0.w, bv0.w, a00))));
            a01 = fmaf(av0.x, bv1.x, fmaf(av0.y, bv1.y, fmaf(av0.z, bv1.z, fmaf(av0.w, bv1.w, a01))));
            a10 = fmaf(av1.x, bv0.x, fmaf(av1.y, bv0.y, fmaf(av1.z, bv0.z, fmaf(av1.w, bv0.w, a10))));
            a11 = fmaf(av1.x, bv1.x, fmaf(av1.y, bv1.y, fmaf(av1.z, bv1.z, fmaf(av1.w, bv1.w, a11))));
        }
        __syncthreads();
    }

    int ia = i0 + ty, ib = i0 + ty + 16;
    int ja = j0 + tx, jb = j0 + tx + 16;
    if (ja <= ia) P[((unsigned)ia * (ia + 1) >> 1) + ja] = a00;
    if (jb <= ia) P[((unsigned)ia * (ia + 1) >> 1) + jb] = a01;
    if (ja <= ib) P[((unsigned)ib * (ib + 1) >> 1) + ja] = a10;
    if (jb <= ib) P[((unsigned)ib * (ib + 1) >> 1) + jb] = a11;
}

// Standalone su kernel (non-fused fallback path only).
__global__ __launch_bounds__(256) void su_kernel(const float* __restrict__ Lu_raw,
                                                 float* __restrict__ P) {
    __shared__ float As[TSU][36];
    __shared__ float Bs[TSU][36];
    su_tile(Lu_raw, P, blockIdx.x, threadIdx.x, As, Bs);
}

// ---------------------------------------------------------------------------
// Sorting-network helpers (u64 and packed v2f).
// ---------------------------------------------------------------------------
__device__ __forceinline__ void ce(unsigned long long& x, unsigned long long& y) {
    unsigned long long a = x, b = y;
    bool c = a < b;
    x = c ? a : b;
    y = c ? b : a;
}
__device__ __forceinline__ void ce(v2f& x, v2f& y) {
    v2f a = __builtin_elementwise_min(x, y);
    v2f b = __builtin_elementwise_max(x, y);
    x = a; y = b;
}

template <typename KT>
__device__ __forceinline__ void sort16(KT* a) {
    #pragma unroll
    for (int p = 1; p < 16; p <<= 1)
        #pragma unroll
        for (int k = p; k >= 1; k >>= 1)
            #pragma unroll
            for (int j = k & (p - 1); j + k < 16; j += 2 * k)
                #pragma unroll
                for (int i = 0; i < k; ++i)
                    if (i + j + k < 16)
                        if (((i + j) / (2 * p)) == ((i + j + k) / (2 * p)))
                            ce(a[i + j], a[i + j + k]);
}

template <typename KT>
__device__ __forceinline__ void cleanup16(KT* a) {
    #pragma unroll
    for (int d = 8; d >= 1; d >>= 1)
        #pragma unroll
        for (int i = 0; i < 16; ++i)
            if ((i & d) == 0) ce(a[i], a[i | d]);
}

// Scalar distance (key rebuild + fallback). Bitwise == per-component packed.
__device__ __forceinline__ float distf(float4 z, float x0, float x1, float x2, float xq) {
    float dot = fmaf(x0, z.x, fmaf(x1, z.y, x2 * z.z));
    return fmaxf(fmaf(-2.0f, dot, xq + z.w), 0.0f);
}

// Packed distances for two point-pairs sharing one candidate z.
__device__ __forceinline__ void dist4(float4 z,
                                      v2f x0a, v2f x1a, v2f x2a, v2f xqa,
                                      v2f x0b, v2f x1b, v2f x2b, v2f xqb,
                                      v2f& da, v2f& db) {
    v2f zx = {z.x, z.x}, zy = {z.y, z.y}, zz = {z.z, z.z}, zw = {z.w, z.w};
    v2f m2 = {-2.0f, -2.0f}, z0 = {0.0f, 0.0f};
    v2f dota = __builtin_elementwise_fma(x0a, zx,
               __builtin_elementwise_fma(x1a, zy, x2a * zz));
    da = __builtin_elementwise_max(
        __builtin_elementwise_fma(m2, dota, xqa + zw), z0);
    v2f dotb = __builtin_elementwise_fma(x0b, zx,
               __builtin_elementwise_fma(x1b, zy, x2b * zz));
    db = __builtin_elementwise_max(
        __builtin_elementwise_fma(m2, dotb, xqb + zw), z0);
}

__device__ __forceinline__ v2f shfl_xor_v2f(v2f v, int mask) {
    unsigned long long u = __builtin_bit_cast(unsigned long long, v);
    u = __shfl_xor(u, mask, 64);
    return __builtin_bit_cast(v2f, u);
}

// Exact serial fallback for one point (rare: some sub overflowed its cap).
__device__ __forceinline__ void serial_knn(const float4* Zs, float x0, float x1,
                                           float x2, float xq,
                                           unsigned long long* dst) {
    unsigned long long R[16];
    #pragma unroll
    for (int i = 0; i < 16; ++i) R[i] = ~0ULL;
    for (int m = 0; m < M_IND; ++m) {
        float d = distf(Zs[m], x0, x1, x2, xq);
        unsigned long long kk =
            ((unsigned long long)__float_as_uint(d) << 32) | (unsigned)m;
        if (kk < R[15]) {
            #pragma unroll
            for (int j = 0; j < 16; ++j) {
                unsigned long long t = R[j];
                bool cc = kk < t;
                R[j] = cc ? kk : t;
                kk = cc ? t : kk;
            }
        }
    }
    #pragma unroll
    for (int i = 0; i < 16; ++i) dst[i] = R[i];
}

// ---------------------------------------------------------------------------
// MODE 2: fused (su tiles in-kernel + device-flag sync). MODE 1: two-kernel.
// MODE 0: no-workspace exact fallback.
// Selection: two-pass threshold scheme, 4 POINTS PER THREAD (two packed
// pairs), 8 subs/point (stripe=128). Each Zs read feeds 4 distances ->
// wave-level ds_read stream halves vs R9 (the binding resource per R11's
// neutral pk-VALU result). 128 class minima/point -> tighter Tstar.
// Lane layout: g = tid>>3 (32 groups), sub = tid&7; group g owns points
// g, g+32 (pair a) and g+64, g+96 (pair b).
// ---------------------------------------------------------------------------
template <int MODE>
__global__ __launch_bounds__(256, 2) void vnngp_kernel(const float* __restrict__ X,
                                                       const float* __restrict__ Z,
                                                       const float* __restrict__ mu,
                                                       float* __restrict__ P,
                                                       const float* __restrict__ Lu_raw,
                                                       unsigned int* __restrict__ ctr,
                                                       float* __restrict__ out) {
    __shared__ __align__(16) char smem[46080];
    float4* Zs = (float4*)smem;                                  // 16 KB
    float* mus = (float*)(smem + 16384);                         // 4 KB
    unsigned long long* qb = (unsigned long long*)(smem + 20480); // 25.6 KB
    int tid = threadIdx.x;

    for (int r = tid; r < M_IND; r += 256) {
        float zx = Z[r * 3 + 0], zy = Z[r * 3 + 1], zz = Z[r * 3 + 2];
        Zs[r] = make_float4(zx, zy, zz, zx * zx + zy * zy + zz * zz);
        mus[r] = mu[r];
    }

    if (MODE == 2) {
        // in-kernel Su tiles (As/Bs alias the qb region: 9216 <= 25600 B).
        // Tile permutation: the 16 grid-stride "extra" tiles are the CHEAP
        // ct=0 single-chunk tiles (ids r(r+1)/2, r=16..31); main tiles skip
        // them so no block stacks two expensive tiles (shorter su tail).
        float (*As)[36] = (float (*)[36])(smem + 20480);
        float (*Bs)[36] = (float (*)[36])(smem + 20480 + 4608);
        int t = blockIdx.x;
        #pragma unroll
        for (int r = 16; r < 32; ++r) {
            int s = (r * (r + 1)) >> 1;
            if (t >= s) ++t;
        }
        su_tile(Lu_raw, P, t, tid, As, Bs);       // contains __syncthreads
        if (blockIdx.x < 16) {
            int r = 16 + blockIdx.x;
            su_tile(Lu_raw, P, (r * (r + 1)) >> 1, tid, As, Bs);
        }
        __syncthreads();                           // P stores drained (vmcnt)
        if (tid == 0) {
            __threadfence();                       // device-scope release
            atomicAdd(ctr, 1u);
        }
    } else {
        __syncthreads();
    }

    {
        int g = tid >> 3, sub = tid & 7;
        int nbase = blockIdx.x * PTS_PER_BLK + g;
        // pair a: points g, g+32 ; pair b: points g+64, g+96
        float xs[4][3];
        #pragma unroll
        for (int q = 0; q < 4; ++q) {
            int n = nbase + q * 32;
            xs[q][0] = X[n * 3 + 0]; xs[q][1] = X[n * 3 + 1]; xs[q][2] = X[n * 3 + 2];
        }
        v2f x0a = {xs[0][0], xs[1][0]}, x1a = {xs[0][1], xs[1][1]}, x2a = {xs[0][2], xs[1][2]};
        v2f x0b = {xs[2][0], xs[3][0]}, x1b = {xs[2][1], xs[3][1]}, x2b = {xs[2][2], xs[3][2]};
        v2f xqa = __builtin_elementwise_fma(x0a, x0a,
                  __builtin_elementwise_fma(x1a, x1a, x2a * x2a));
        v2f xqb = __builtin_elementwise_fma(x0b, x0b,
                  __builtin_elementwise_fma(x1b, x1b, x2b * x2b));
        int mbase = sub << 7;   // 128-candidate stripe
        int rot = sub;          // 8 distinct bank quads across subs

        // ---- Pass 1: 16 packed class minima per pair ----
        v2f Ta[16], Tb[16];
        #pragma unroll
        for (int j = 0; j < 16; ++j) { Ta[j] = (v2f){3.4e38f, 3.4e38f}; Tb[j] = Ta[j]; }
        #pragma unroll 1
        for (int c = 0; c < 8; ++c) {
            int base = mbase + (c << 4);
            #pragma unroll
            for (int j = 0; j < 16; ++j) {
                int m = base + ((j + rot) & 15);
                v2f da, db;
                dist4(Zs[m], x0a, x1a, x2a, xqa, x0b, x1b, x2b, xqb, da, db);
                Ta[j] = __builtin_elementwise_min(Ta[j], da);
                Tb[j] = __builtin_elementwise_min(Tb[j], db);
            }
        }
        sort16(Ta);
        sort16(Tb);
        #pragma unroll
        for (int round = 1; round <= 4; round <<= 1) {
            v2f oa[16], ob[16];
            #pragma unroll
            for (int i = 0; i < 16; ++i) {
                oa[i] = shfl_xor_v2f(Ta[i], round);
                ob[i] = shfl_xor_v2f(Tb[i], round);
            }
            #pragma unroll
            for (int i = 0; i < 16; ++i) {
                Ta[i] = __builtin_elementwise_min(Ta[i], oa[15 - i]);
                Tb[i] = __builtin_elementwise_min(Tb[i], ob[15 - i]);
            }
            cleanup16(Ta);
            cleanup16(Tb);
        }
        v2f Tsta = Ta[15], Tstb = Tb[15];   // per-point bound >= true 16th-smallest

        // ---- Pass 2: collect indices with d <= Tstar (u16, cap 12/sub) ----
        unsigned short* myc[4];
        int cnt[4] = {0, 0, 0, 0};
        #pragma unroll
        for (int q = 0; q < 4; ++q)
            myc[q] = ((unsigned short*)qb) + (g + q * 32) * (QSTRIDE * 4) + sub * 12;
        #pragma unroll 1
        for (int c = 0; c < 8; ++c) {
            int base = mbase + (c << 4);
            #pragma unroll
            for (int j = 0; j < 16; ++j) {
                int m = base + ((j + rot) & 15);
                v2f da, db;
                dist4(Zs[m], x0a, x1a, x2a, xqa, x0b, x1b, x2b, xqb, da, db);
                if (da.x <= Tsta.x) { if (cnt[0] < 12) myc[0][cnt[0]] = (unsigned short)m; ++cnt[0]; }
                if (da.y <= Tsta.y) { if (cnt[1] < 12) myc[1][cnt[1]] = (unsigned short)m; ++cnt[1]; }
                if (db.x <= Tstb.x) { if (cnt[2] < 12) myc[2][cnt[2]] = (unsigned short)m; ++cnt[2]; }
                if (db.y <= Tstb.y) { if (cnt[3] < 12) myc[3][cnt[3]] = (unsigned short)m; ++cnt[3]; }
            }
        }

        // ---- finalize each of the 4 points (sequential; 8 lanes merge) ----
        #pragma unroll 1
        for (int q = 0; q < 4; ++q) {
            int p = g + q * 32;
            int ovf = cnt[q] > 12 ? 1 : 0;
            ovf |= __shfl_xor(ovf, 1, 64);
            ovf |= __shfl_xor(ovf, 2, 64);
            ovf |= __shfl_xor(ovf, 4, 64);
            float px0 = xs[q][0], px1 = xs[q][1], px2 = xs[q][2];
            float pxq = (q == 0) ? xqa.x : (q == 1) ? xqa.y : (q == 2) ? xqb.x : xqb.y;
            if (!ovf) {
                const unsigned long long* m64 = (const unsigned long long*)myc[q];
                unsigned long long raw[3] = {m64[0], m64[1], m64[2]};
                unsigned long long C[16];
                #pragma unroll
                for (int i = 0; i < 16; ++i) {
                    int m = (i < 12) ? (int)((raw[i >> 2] >> ((i & 3) * 16)) & 0x3FF) : 0;
                    float d = distf(Zs[m], px0, px1, px2, pxq);
                    unsigned long long key =
                        ((unsigned long long)__float_as_uint(d) << 32) | (unsigned)m;
                    C[i] = (i < cnt[q]) ? key : ~0ULL;
                }
                sort16(C);
                #pragma unroll
                for (int round = 1; round <= 4; round <<= 1) {
                    unsigned long long o[16];
                    #pragma unroll
                    for (int i = 0; i < 16; ++i) o[i] = __shfl_xor(C[i], round, 64);
                    #pragma unroll
                    for (int i = 0; i < 16; ++i) {
                        unsigned long long b = o[15 - i];
                        C[i] = C[i] < b ? C[i] : b;
                    }
                    cleanup16(C);
                }
                if (sub == 0) {   // all lanes' reads precede (wave lockstep)
                    #pragma unroll
                    for (int i = 0; i < 16; ++i) qb[p * QSTRIDE + i] = C[i];
                }
            } else if (sub == 0) {
                serial_knn(Zs, px0, px1, px2, pxq, &qb[p * QSTRIDE]);
            }
        }
    }
    __syncthreads();

    if (MODE == 2) {
        // Wait for all blocks' Su tiles (selection above overlapped them).
        if (tid == 0) {
            while (__hip_atomic_load(ctr, __ATOMIC_ACQUIRE, __HIP_MEMORY_SCOPE_AGENT)
                   < (unsigned)GRID_BLKS)
                __builtin_amdgcn_s_sleep(8);
        }
        __syncthreads();
    }
    if (tid >= PTS_PER_BLK) return;

    // ---- Phase 2: local GP, one thread per point ----
    int n = blockIdx.x * PTS_PER_BLK + tid;
    int idx[KNN];
    float kv[KNN];
    float nx[KNN], ny[KNN], nz[KNN], nq[KNN];
    #pragma unroll
    for (int a = 0; a < KNN; ++a) {
        unsigned long long k = qb[tid * QSTRIDE + a];
        idx[a] = (int)(k & 0xFFFFFFFFULL);
        float d = __uint_as_float((unsigned)(k >> 32));
        kv[a] = __expf(-0.5f * d);            // lKxz entries
        float4 z = Zs[idx[a]];
        nx[a] = z.x; ny[a] = z.y; nz[a] = z.z; nq[a] = z.w;
    }

    // A = lKzz + JITTER*I (lower tri); diag = 1 + 2*JITTER (Kzz_j = L L^T).
    float A[KNN * (KNN + 1) / 2];
    #pragma unroll
    for (int r = 0; r < KNN; ++r) {
        A[r * (r + 1) / 2 + r] = 1.0f + 2.0f * JITTER;
        #pragma unroll
        for (int c = 0; c < r; ++c) {
            float dd = nq[r] + nq[c]
                     - 2.0f * (nx[r] * nx[c] + ny[r] * ny[c] + nz[r] * nz[c]);
            dd = fmaxf(dd, 0.0f);
            A[r * (r + 1) / 2 + c] = __expf(-0.5f * dd);
        }
    }

    // In-place Cholesky; store 1/L[c][c] in the diagonal slot.
    #pragma unroll
    for (int c = 0; c < KNN; ++c) {
        float diag = A[c * (c + 1) / 2 + c];
        #pragma unroll
        for (int k = 0; k < c; ++k) {
            float l = A[c * (c + 1) / 2 + k];
            diag = fmaf(-l, l, diag);
        }
        float s = sqrtf(fmaxf(diag, 1e-12f));
        float rinv = 1.0f / s;
        A[c * (c + 1) / 2 + c] = rinv;
        #pragma unroll
        for (int r = c + 1; r < KNN; ++r) {
            float v = A[r * (r + 1) / 2 + c];
            #pragma unroll
            for (int k = 0; k < c; ++k)
                v = fmaf(-A[r * (r + 1) / 2 + k], A[c * (c + 1) / 2 + k], v);
            A[r * (r + 1) / 2 + c] = v * rinv;
        }
    }

    // Solve A w = kv (forward then backward).
    float w[KNN];
    #pragma unroll
    for (int r = 0; r < KNN; ++r) {
        float v = kv[r];
        #pragma unroll
        for (int c = 0; c < r; ++c) v = fmaf(-A[r * (r + 1) / 2 + c], w[c], v);
        w[r] = v * A[r * (r + 1) / 2 + r];
    }
    #pragma unroll
    for (int r = KNN - 1; r >= 0; --r) {
        float v = w[r];
        #pragma unroll
        for (int c = r + 1; c < KNN; ++c) v = fmaf(-A[c * (c + 1) / 2 + r], w[c], v);
        w[r] = v * A[r * (r + 1) / 2 + r];
    }

    // W lKzz W^T = w.k - JITTER*||w||^2   (A w = k, lKzz = A - JITTER*I)
    float wk = 0.f, ww = 0.f, mean = 0.f;
    #pragma unroll
    for (int a = 0; a < KNN; ++a) {
        wk = fmaf(w[a], kv[a], wk);
        ww = fmaf(w[a], w[a], ww);
        mean = fmaf(w[a], mus[idx[a]], mean);
    }

    // qs = w^T Su[idx,idx] w
    float qs = 0.f;
    if (MODE != 0) {
        #pragma unroll
        for (int r = 0; r < KNN; ++r) {
            int a = idx[r];
            float wr = w[r];
            float rowacc = 0.f;
            #pragma unroll
            for (int c = 0; c < r; ++c) {
                int b = idx[c];
                int hi = a > b ? a : b;
                int lo = a > b ? b : a;
                rowacc = fmaf(w[c], P[((unsigned)hi * (hi + 1) >> 1) + lo], rowacc);
            }
            qs = fmaf(wr, fmaf(wr, P[((unsigned)a * (a + 1) >> 1) + a], 2.0f * rowacc), qs);
        }
    } else {
        // On-demand fallback: qs = sum_k (sum_a w_a * Lu[idx_a, k])^2
        int si[KNN]; float sw[KNN];
        #pragma unroll
        for (int a = 0; a < KNN; ++a) { si[a] = idx[a]; sw[a] = w[a]; }
        #pragma unroll
        for (int a = 1; a < KNN; ++a) {
            int iv = si[a]; float wv = sw[a];
            int b = a - 1;
            while (b >= 0 && si[b] > iv) { si[b + 1] = si[b]; sw[b + 1] = sw[b]; --b; }
            si[b + 1] = iv; sw[b + 1] = wv;
        }
        int s = 0;
        int kend = si[KNN - 1];
        for (int k = 0; k <= kend; ++k) {
            float v = 0.f;
            if (s < KNN && si[s] == k) {
                v = sw[s] * __expf(Lu_raw[(unsigned)k * M_IND + k]);
                ++s;
            }
            for (int a = s; a < KNN; ++a)
                v = fmaf(sw[a], Lu_raw[(unsigned)si[a] * M_IND + k], v);
            qs = fmaf(v, v, qs);
        }
    }

    float cov = 1.0f - (wk - JITTER * ww) + qs;
    float sd = sqrtf(fmaxf(cov, 0.05f));
    out[n] = mean;
    out[N_PTS + n] = sd;
}

// ---------------------------------------------------------------------------
extern "C" void kernel_launch(void* const* d_in, const int* in_sizes, int n_in,
                              void* d_out, int out_size, void* d_ws, size_t ws_size,
                              hipStream_t stream) {
    const float* X      = (const float*)d_in[0];
    const float* Z      = (const float*)d_in[1];
    const float* Lu_raw = (const float*)d_in[2];
    const float* mu     = (const float*)d_in[3];
    float* out = (float*)d_out;

    if (ws_size >= PACKED_BYTES + 64) {
        // Fused: P + completion counter live in d_ws.
        float* P = (float*)d_ws;
        unsigned int* ctr = (unsigned int*)((char*)d_ws + PACKED_BYTES);
        hipMemsetAsync(ctr, 0, sizeof(unsigned int), stream);
        vnngp_kernel<2><<<GRID_BLKS, 256, 0, stream>>>(X, Z, mu, P, Lu_raw, ctr, out);
    } else if (ws_size >= PACKED_BYTES) {
        float* P = (float*)d_ws;
        su_kernel<<<SU_BLOCKS, 256, 0, stream>>>(Lu_raw, P);
        vnngp_kernel<1><<<GRID_BLKS, 256, 0, stream>>>(X, Z, mu, P, Lu_raw, nullptr, out);
    } else {
        vnngp_kernel<0><<<GRID_BLKS, 256, 0, stream>>>(X, Z, mu, nullptr, Lu_raw, nullptr, out);
    }
}

// Round 13
// 171.222 us; speedup vs baseline: 1.1184x; 1.1184x over previous
//
#include <hip/hip_runtime.h>
#include <math.h>

#define N_PTS 65536
#define M_IND 1024
#define KNN 16
#define JITTER 1e-4f

// Packed lower-triangular Su: P[i*(i+1)/2 + j], j <= i.
#define PACKED_FLOATS (M_IND * (M_IND + 1) / 2)               // 524800
#define PACKED_BYTES  ((size_t)PACKED_FLOATS * sizeof(float)) // 2,099,200 B

#define TSU 32
#define SU_BLOCKS 528          // 32*33/2 triangular tiles
#define PTS_PER_BLK 128
#define QSTRIDE 17             // u64 per point row (136 B)
#define GRID_BLKS (N_PTS / PTS_PER_BLK)   // 512

// ---------------------------------------------------------------------------
// One 32x32 Su tile (packed tril(Lu Lu^T)). As/Bs are LDS scratch.
// ---------------------------------------------------------------------------
__device__ __forceinline__ void su_tile(const float* __restrict__ Lu_raw,
                                        float* __restrict__ P,
                                        int bid, int tid,
                                        float (*As)[36], float (*Bs)[36]) {
    int rt = (int)((sqrtf(8.0f * (float)bid + 1.0f) - 1.0f) * 0.5f);
    while ((rt + 1) * (rt + 2) / 2 <= bid) ++rt;
    while (rt * (rt + 1) / 2 > bid) --rt;
    int ct = bid - rt * (rt + 1) / 2;   // ct <= rt
    int i0 = rt * TSU, j0 = ct * TSU;

    int tx = tid & 15, ty = tid >> 4;
    int sr = tid >> 3, sc = (tid & 7) << 2;
    float a00 = 0.f, a01 = 0.f, a10 = 0.f, a11 = 0.f;

    int nch = ct + 1;                      // k-chunks of 32 (k <= j0+31)
    int gi = i0 + sr, gj = j0 + sr;
    float4 pa = *(const float4*)(Lu_raw + (unsigned)gi * M_IND + sc);
    float4 pb = *(const float4*)(Lu_raw + (unsigned)gj * M_IND + sc);

    for (int c = 0; c < nch; ++c) {
        int gk = (c << 5) + sc;
        float aa[4] = {pa.x, pa.y, pa.z, pa.w};
        float bb[4] = {pb.x, pb.y, pb.z, pb.w};
        #pragma unroll
        for (int q = 0; q < 4; ++q) {
            int k = gk + q;
            aa[q] = (k < gi) ? aa[q] : ((k == gi) ? __expf(aa[q]) : 0.0f);
            bb[q] = (k < gj) ? bb[q] : ((k == gj) ? __expf(bb[q]) : 0.0f);
        }
        *(float4*)&As[sr][sc] = make_float4(aa[0], aa[1], aa[2], aa[3]);
        *(float4*)&Bs[sr][sc] = make_float4(bb[0], bb[1], bb[2], bb[3]);
        __syncthreads();
        if (c + 1 < nch) {
            int kn = ((c + 1) << 5) + sc;
            pa = *(const float4*)(Lu_raw + (unsigned)gi * M_IND + kn);
            pb = *(const float4*)(Lu_raw + (unsigned)gj * M_IND + kn);
        }
        #pragma unroll
        for (int kk = 0; kk < 32; kk += 4) {
            float4 av0 = *(const float4*)&As[ty][kk];
            float4 av1 = *(const float4*)&As[ty + 16][kk];
            float4 bv0 = *(const float4*)&Bs[tx][kk];
            float4 bv1 = *(const float4*)&Bs[tx + 16][kk];
            a00 = fmaf(av0.x, bv0.x, fmaf(av0.y, bv0.y, fmaf(av0.z, bv0.z, fmaf(av0.w, bv0.w, a00))));
            a01 = fmaf(av0.x, bv1.x, fmaf(av0.y, bv1.y, fmaf(av0.z, bv1.z, fmaf(av0.w, bv1.w, a01))));
            a10 = fmaf(av1.x, bv0.x, fmaf(av1.y, bv0.y, fmaf(av1.z, bv0.z, fmaf(av1.w, bv0.w, a10))));
            a11 = fmaf(av1.x, bv1.x, fmaf(av1.y, bv1.y, fmaf(av1.z, bv1.z, fmaf(av1.w, bv1.w, a11))));
        }
        __syncthreads();
    }

    int ia = i0 + ty, ib = i0 + ty + 16;
    int ja = j0 + tx, jb = j0 + tx + 16;
    if (ja <= ia) P[((unsigned)ia * (ia + 1) >> 1) + ja] = a00;
    if (jb <= ia) P[((unsigned)ia * (ia + 1) >> 1) + jb] = a01;
    if (ja <= ib) P[((unsigned)ib * (ib + 1) >> 1) + ja] = a10;
    if (jb <= ib) P[((unsigned)ib * (ib + 1) >> 1) + jb] = a11;
}

// Standalone su kernel (non-fused fallback path only).
__global__ __launch_bounds__(256) void su_kernel(const float* __restrict__ Lu_raw,
                                                 float* __restrict__ P) {
    __shared__ float As[TSU][36];
    __shared__ float Bs[TSU][36];
    su_tile(Lu_raw, P, blockIdx.x, threadIdx.x, As, Bs);
}

// ---------------------------------------------------------------------------
// Sorting-network helpers.
// ---------------------------------------------------------------------------
__device__ __forceinline__ void ce(unsigned long long& x, unsigned long long& y) {
    unsigned long long a = x, b = y;
    bool c = a < b;
    x = c ? a : b;
    y = c ? b : a;
}
__device__ __forceinline__ void ce(float& x, float& y) {
    float a = fminf(x, y), b = fmaxf(x, y);
    x = a; y = b;
}

template <typename KT>
__device__ __forceinline__ void sort16(KT* a) {
    #pragma unroll
    for (int p = 1; p < 16; p <<= 1)
        #pragma unroll
        for (int k = p; k >= 1; k >>= 1)
            #pragma unroll
            for (int j = k & (p - 1); j + k < 16; j += 2 * k)
                #pragma unroll
                for (int i = 0; i < k; ++i)
                    if (i + j + k < 16)
                        if (((i + j) / (2 * p)) == ((i + j + k) / (2 * p)))
                            ce(a[i + j], a[i + j + k]);
}

template <typename KT>
__device__ __forceinline__ void cleanup16(KT* a) {
    #pragma unroll
    for (int d = 8; d >= 1; d >>= 1)
        #pragma unroll
        for (int i = 0; i < 16; ++i)
            if ((i & d) == 0) ce(a[i], a[i | d]);
}

// Identical-bits distance (pass 1, pass 2, read-back, fallback).
__device__ __forceinline__ float distf(float4 z, float x0, float x1, float x2, float xq) {
    float dot = fmaf(x0, z.x, fmaf(x1, z.y, x2 * z.z));
    return fmaxf(fmaf(-2.0f, dot, xq + z.w), 0.0f);
}

// ---------------------------------------------------------------------------
// MODE 2: fused (su tiles in-kernel + device-flag sync). MODE 1: two-kernel.
// MODE 0: no-workspace exact fallback.
// Selection (measured-best config, R9/R10): two-pass threshold scheme,
// 2 points/thread, 4 subs/point, 256 threads/block, 512 blocks.
// ---------------------------------------------------------------------------
template <int MODE>
__global__ __launch_bounds__(256, 2) void vnngp_kernel(const float* __restrict__ X,
                                                       const float* __restrict__ Z,
                                                       const float* __restrict__ mu,
                                                       float* __restrict__ P,
                                                       const float* __restrict__ Lu_raw,
                                                       unsigned int* __restrict__ ctr,
                                                       float* __restrict__ out) {
    __shared__ __align__(16) char smem[37888];
    float4* Zs = (float4*)smem;                                  // 16 KB
    float* mus = (float*)(smem + 16384);                         // 4 KB
    unsigned long long* qb = (unsigned long long*)(smem + 20480); // 17 KB
    int tid = threadIdx.x;

    for (int r = tid; r < M_IND; r += 256) {
        float zx = Z[r * 3 + 0], zy = Z[r * 3 + 1], zz = Z[r * 3 + 2];
        Zs[r] = make_float4(zx, zy, zz, zx * zx + zy * zy + zz * zz);
        mus[r] = mu[r];
    }

    if (MODE == 2) {
        // In-kernel Su tiles (As/Bs alias the qb region: 9216 <= 17408 B).
        // Tile permutation: the 16 grid-stride "extra" tiles are the CHEAP
        // ct=0 single-chunk tiles (ids r(r+1)/2, r=16..31); the main
        // assignment skips them, so no block stacks a second expensive tile
        // (R10 stacked the 16 rt=31 tiles on blocks 0..15 -> longer tail).
        float (*As)[36] = (float (*)[36])(smem + 20480);
        float (*Bs)[36] = (float (*)[36])(smem + 20480 + 4608);
        int t = blockIdx.x;
        #pragma unroll
        for (int r = 16; r < 32; ++r) {
            int s = (r * (r + 1)) >> 1;
            if (t >= s) ++t;
        }
        su_tile(Lu_raw, P, t, tid, As, Bs);       // contains __syncthreads
        if (blockIdx.x < 16) {
            int r = 16 + blockIdx.x;
            su_tile(Lu_raw, P, (r * (r + 1)) >> 1, tid, As, Bs);
        }
        __syncthreads();                           // P stores drained (vmcnt)
        if (tid == 0) {
            __threadfence();                       // device-scope release
            atomicAdd(ctr, 1u);
        }
    } else {
        __syncthreads();
    }

    {
        int pt = tid >> 2, sub = tid & 3;     // pt 0..63, quad handles pt & pt+64
        int nA = blockIdx.x * PTS_PER_BLK + pt;
        int nB = nA + 64;
        float xA0 = X[nA * 3 + 0], xA1 = X[nA * 3 + 1], xA2 = X[nA * 3 + 2];
        float xB0 = X[nB * 3 + 0], xB1 = X[nB * 3 + 1], xB2 = X[nB * 3 + 2];
        float xqA = fmaf(xA0, xA0, fmaf(xA1, xA1, xA2 * xA2));
        float xqB = fmaf(xB0, xB0, fmaf(xB1, xB1, xB2 * xB2));
        int mbase = sub << 8;
        int rot = sub << 1;   // subs land on disjoint bank quads

        // ---- Pass 1: 16 interleaved class minima per point (f32) ----
        float TA[16], TB[16];
        #pragma unroll
        for (int j = 0; j < 16; ++j) { TA[j] = 3.4e38f; TB[j] = 3.4e38f; }
        #pragma unroll 1
        for (int c = 0; c < 16; ++c) {
            int base = mbase + (c << 4);
            #pragma unroll
            for (int j = 0; j < 16; ++j) {
                int m = base + ((j + rot) & 15);
                float4 z = Zs[m];
                TA[j] = fminf(TA[j], distf(z, xA0, xA1, xA2, xqA));
                TB[j] = fminf(TB[j], distf(z, xB0, xB1, xB2, xqB));
            }
        }
        sort16(TA);
        sort16(TB);
        #pragma unroll
        for (int round = 1; round <= 2; round <<= 1) {
            float oA[16], oB[16];
            #pragma unroll
            for (int i = 0; i < 16; ++i) {
                oA[i] = __shfl_xor(TA[i], round, 64);
                oB[i] = __shfl_xor(TB[i], round, 64);
            }
            #pragma unroll
            for (int i = 0; i < 16; ++i) {
                TA[i] = fminf(TA[i], oA[15 - i]);
                TB[i] = fminf(TB[i], oB[15 - i]);
            }
            cleanup16(TA);
            cleanup16(TB);
        }
        float TstarA = TA[15], TstarB = TB[15];

        // ---- Pass 2: collect indices with d <= Tstar (u16, cap 16/sub) ----
        unsigned short* mycA = ((unsigned short*)qb) + pt * (QSTRIDE * 4) + sub * 16;
        unsigned short* mycB = ((unsigned short*)qb) + (pt + 64) * (QSTRIDE * 4) + sub * 16;
        int cntA = 0, cntB = 0;
        #pragma unroll 1
        for (int c = 0; c < 16; ++c) {
            int base = mbase + (c << 4);
            #pragma unroll
            for (int j = 0; j < 16; ++j) {
                int m = base + ((j + rot) & 15);
                float4 z = Zs[m];
                float dA = distf(z, xA0, xA1, xA2, xqA);
                float dB = distf(z, xB0, xB1, xB2, xqB);
                if (dA <= TstarA) { if (cntA < 16) mycA[cntA] = (unsigned short)m; ++cntA; }
                if (dB <= TstarB) { if (cntB < 16) mycB[cntB] = (unsigned short)m; ++cntB; }
            }
        }

        int ovfA = cntA > 16 ? 1 : 0;
        ovfA |= __shfl_xor(ovfA, 1, 64);
        ovfA |= __shfl_xor(ovfA, 2, 64);
        int ovfB = cntB > 16 ? 1 : 0;
        ovfB |= __shfl_xor(ovfB, 1, 64);
        ovfB |= __shfl_xor(ovfB, 2, 64);

        // ---- finalize point A ----
        if (!ovfA) {
            const unsigned long long* m64 = (const unsigned long long*)mycA;
            unsigned long long raw[4] = {m64[0], m64[1], m64[2], m64[3]};
            unsigned long long C[16];
            #pragma unroll
            for (int i = 0; i < 16; ++i) {
                int m = (int)((raw[i >> 2] >> ((i & 3) * 16)) & 0x3FF);
                float d = distf(Zs[m], xA0, xA1, xA2, xqA);
                unsigned long long key =
                    ((unsigned long long)__float_as_uint(d) << 32) | (unsigned)m;
                C[i] = (i < cntA) ? key : ~0ULL;
            }
            sort16(C);
            #pragma unroll
            for (int round = 1; round <= 2; round <<= 1) {
                unsigned long long o[16];
                #pragma unroll
                for (int i = 0; i < 16; ++i) o[i] = __shfl_xor(C[i], round, 64);
                #pragma unroll
                for (int i = 0; i < 16; ++i) {
                    unsigned long long b = o[15 - i];
                    C[i] = C[i] < b ? C[i] : b;
                }
                cleanup16(C);
            }
            if (sub == 0) {
                #pragma unroll
                for (int i = 0; i < 16; ++i) qb[pt * QSTRIDE + i] = C[i];
            }
        } else if (sub == 0) {
            unsigned long long R[16];
            #pragma unroll
            for (int i = 0; i < 16; ++i) R[i] = ~0ULL;
            for (int m = 0; m < M_IND; ++m) {
                float d = distf(Zs[m], xA0, xA1, xA2, xqA);
                unsigned long long kk =
                    ((unsigned long long)__float_as_uint(d) << 32) | (unsigned)m;
                if (kk < R[15]) {
                    #pragma unroll
                    for (int j = 0; j < 16; ++j) {
                        unsigned long long t = R[j];
                        bool cc = kk < t;
                        R[j] = cc ? kk : t;
                        kk = cc ? t : kk;
                    }
                }
            }
            #pragma unroll
            for (int i = 0; i < 16; ++i) qb[pt * QSTRIDE + i] = R[i];
        }

        // ---- finalize point B ----
        if (!ovfB) {
            const unsigned long long* m64 = (const unsigned long long*)mycB;
            unsigned long long raw[4] = {m64[0], m64[1], m64[2], m64[3]};
            unsigned long long C[16];
            #pragma unroll
            for (int i = 0; i < 16; ++i) {
                int m = (int)((raw[i >> 2] >> ((i & 3) * 16)) & 0x3FF);
                float d = distf(Zs[m], xB0, xB1, xB2, xqB);
                unsigned long long key =
                    ((unsigned long long)__float_as_uint(d) << 32) | (unsigned)m;
                C[i] = (i < cntB) ? key : ~0ULL;
            }
            sort16(C);
            #pragma unroll
            for (int round = 1; round <= 2; round <<= 1) {
                unsigned long long o[16];
                #pragma unroll
                for (int i = 0; i < 16; ++i) o[i] = __shfl_xor(C[i], round, 64);
                #pragma unroll
                for (int i = 0; i < 16; ++i) {
                    unsigned long long b = o[15 - i];
                    C[i] = C[i] < b ? C[i] : b;
                }
                cleanup16(C);
            }
            if (sub == 0) {
                #pragma unroll
                for (int i = 0; i < 16; ++i) qb[(pt + 64) * QSTRIDE + i] = C[i];
            }
        } else if (sub == 0) {
            unsigned long long R[16];
            #pragma unroll
            for (int i = 0; i < 16; ++i) R[i] = ~0ULL;
            for (int m = 0; m < M_IND; ++m) {
                float d = distf(Zs[m], xB0, xB1, xB2, xqB);
                unsigned long long kk =
                    ((unsigned long long)__float_as_uint(d) << 32) | (unsigned)m;
                if (kk < R[15]) {
                    #pragma unroll
                    for (int j = 0; j < 16; ++j) {
                        unsigned long long t = R[j];
                        bool cc = kk < t;
                        R[j] = cc ? kk : t;
                        kk = cc ? t : kk;
                    }
                }
            }
            #pragma unroll
            for (int i = 0; i < 16; ++i) qb[(pt + 64) * QSTRIDE + i] = R[i];
        }
    }
    __syncthreads();

    if (MODE == 2) {
        // Wait for all blocks' Su tiles (selection above overlapped them).
        if (tid == 0) {
            while (__hip_atomic_load(ctr, __ATOMIC_ACQUIRE, __HIP_MEMORY_SCOPE_AGENT)
                   < (unsigned)GRID_BLKS)
                __builtin_amdgcn_s_sleep(8);
        }
        __syncthreads();
    }
    if (tid >= PTS_PER_BLK) return;

    // ---- Phase 2: local GP, one thread per point ----
    int n = blockIdx.x * PTS_PER_BLK + tid;
    int idx[KNN];
    float kv[KNN];
    float nx[KNN], ny[KNN], nz[KNN], nq[KNN];
    #pragma unroll
    for (int a = 0; a < KNN; ++a) {
        unsigned long long k = qb[tid * QSTRIDE + a];
        idx[a] = (int)(k & 0xFFFFFFFFULL);
        float d = __uint_as_float((unsigned)(k >> 32));
        kv[a] = __expf(-0.5f * d);            // lKxz entries
        float4 z = Zs[idx[a]];
        nx[a] = z.x; ny[a] = z.y; nz[a] = z.z; nq[a] = z.w;
    }

    // A = lKzz + JITTER*I (lower tri); diag = 1 + 2*JITTER (Kzz_j = L L^T).
    float A[KNN * (KNN + 1) / 2];
    #pragma unroll
    for (int r = 0; r < KNN; ++r) {
        A[r * (r + 1) / 2 + r] = 1.0f + 2.0f * JITTER;
        #pragma unroll
        for (int c = 0; c < r; ++c) {
            float dd = nq[r] + nq[c]
                     - 2.0f * (nx[r] * nx[c] + ny[r] * ny[c] + nz[r] * nz[c]);
            dd = fmaxf(dd, 0.0f);
            A[r * (r + 1) / 2 + c] = __expf(-0.5f * dd);
        }
    }

    // In-place Cholesky; store 1/L[c][c] in the diagonal slot.
    #pragma unroll
    for (int c = 0; c < KNN; ++c) {
        float diag = A[c * (c + 1) / 2 + c];
        #pragma unroll
        for (int k = 0; k < c; ++k) {
            float l = A[c * (c + 1) / 2 + k];
            diag = fmaf(-l, l, diag);
        }
        float s = sqrtf(fmaxf(diag, 1e-12f));
        float rinv = 1.0f / s;
        A[c * (c + 1) / 2 + c] = rinv;
        #pragma unroll
        for (int r = c + 1; r < KNN; ++r) {
            float v = A[r * (r + 1) / 2 + c];
            #pragma unroll
            for (int k = 0; k < c; ++k)
                v = fmaf(-A[r * (r + 1) / 2 + k], A[c * (c + 1) / 2 + k], v);
            A[r * (r + 1) / 2 + c] = v * rinv;
        }
    }

    // Solve A w = kv (forward then backward).
    float w[KNN];
    #pragma unroll
    for (int r = 0; r < KNN; ++r) {
        float v = kv[r];
        #pragma unroll
        for (int c = 0; c < r; ++c) v = fmaf(-A[r * (r + 1) / 2 + c], w[c], v);
        w[r] = v * A[r * (r + 1) / 2 + r];
    }
    #pragma unroll
    for (int r = KNN - 1; r >= 0; --r) {
        float v = w[r];
        #pragma unroll
        for (int c = r + 1; c < KNN; ++c) v = fmaf(-A[c * (c + 1) / 2 + r], w[c], v);
        w[r] = v * A[r * (r + 1) / 2 + r];
    }

    // W lKzz W^T = w.k - JITTER*||w||^2   (A w = k, lKzz = A - JITTER*I)
    float wk = 0.f, ww = 0.f, mean = 0.f;
    #pragma unroll
    for (int a = 0; a < KNN; ++a) {
        wk = fmaf(w[a], kv[a], wk);
        ww = fmaf(w[a], w[a], ww);
        mean = fmaf(w[a], mus[idx[a]], mean);
    }

    // qs = w^T Su[idx,idx] w
    float qs = 0.f;
    if (MODE != 0) {
        #pragma unroll
        for (int r = 0; r < KNN; ++r) {
            int a = idx[r];
            float wr = w[r];
            float rowacc = 0.f;
            #pragma unroll
            for (int c = 0; c < r; ++c) {
                int b = idx[c];
                int hi = a > b ? a : b;
                int lo = a > b ? b : a;
                rowacc = fmaf(w[c], P[((unsigned)hi * (hi + 1) >> 1) + lo], rowacc);
            }
            qs = fmaf(wr, fmaf(wr, P[((unsigned)a * (a + 1) >> 1) + a], 2.0f * rowacc), qs);
        }
    } else {
        // On-demand fallback: qs = sum_k (sum_a w_a * Lu[idx_a, k])^2
        int si[KNN]; float sw[KNN];
        #pragma unroll
        for (int a = 0; a < KNN; ++a) { si[a] = idx[a]; sw[a] = w[a]; }
        #pragma unroll
        for (int a = 1; a < KNN; ++a) {
            int iv = si[a]; float wv = sw[a];
            int b = a - 1;
            while (b >= 0 && si[b] > iv) { si[b + 1] = si[b]; sw[b + 1] = sw[b]; --b; }
            si[b + 1] = iv; sw[b + 1] = wv;
        }
        int s = 0;
        int kend = si[KNN - 1];
        for (int k = 0; k <= kend; ++k) {
            float v = 0.f;
            if (s < KNN && si[s] == k) {
                v = sw[s] * __expf(Lu_raw[(unsigned)k * M_IND + k]);
                ++s;
            }
            for (int a = s; a < KNN; ++a)
                v = fmaf(sw[a], Lu_raw[(unsigned)si[a] * M_IND + k], v);
            qs = fmaf(v, v, qs);
        }
    }

    float cov = 1.0f - (wk - JITTER * ww) + qs;
    float sd = sqrtf(fmaxf(cov, 0.05f));
    out[n] = mean;
    out[N_PTS + n] = sd;
}

// ---------------------------------------------------------------------------
extern "C" void kernel_launch(void* const* d_in, const int* in_sizes, int n_in,
                              void* d_out, int out_size, void* d_ws, size_t ws_size,
                              hipStream_t stream) {
    const float* X      = (const float*)d_in[0];
    const float* Z      = (const float*)d_in[1];
    const float* Lu_raw = (const float*)d_in[2];
    const float* mu     = (const float*)d_in[3];
    float* out = (float*)d_out;

    if (ws_size >= PACKED_BYTES + 64) {
        // Fused: P + completion counter live in d_ws.
        float* P = (float*)d_ws;
        unsigned int* ctr = (unsigned int*)((char*)d_ws + PACKED_BYTES);
        hipMemsetAsync(ctr, 0, sizeof(unsigned int), stream);
        vnngp_kernel<2><<<GRID_BLKS, 256, 0, stream>>>(X, Z, mu, P, Lu_raw, ctr, out);
    } else if (ws_size >= PACKED_BYTES) {
        float* P = (float*)d_ws;
        su_kernel<<<SU_BLOCKS, 256, 0, stream>>>(Lu_raw, P);
        vnngp_kernel<1><<<GRID_BLKS, 256, 0, stream>>>(X, Z, mu, P, Lu_raw, nullptr, out);
    } else {
        vnngp_kernel<0><<<GRID_BLKS, 256, 0, stream>>>(X, Z, mu, nullptr, Lu_raw, nullptr, out);
    }
}